// Round 5
// baseline (200.912 us; speedup 1.0000x reference)
//
#include <hip/hip_runtime.h>
#include <hip/hip_bf16.h>

#define SEQ_LEN 2048
#define NBATCH 2
#define DM 1024
#define NH 16
#define HD 64
#define NR (NBATCH * SEQ_LEN)  // 4096 rows
#define NQKV (3 * DM)          // 3072 fused QKV cols
#define LDQK 2048              // QK buffer leading dim (Q cols 0..1023, K 1024..2047)

typedef __attribute__((ext_vector_type(8))) short bf16x8;
typedef __attribute__((ext_vector_type(4))) float f32x4;
typedef __attribute__((ext_vector_type(16))) float f32x16;

__device__ __forceinline__ short f2b(float f) {
    __hip_bfloat16 h = __float2bfloat16(f);
    return *reinterpret_cast<short*>(&h);
}

// async global->LDS 16B copy
__device__ __forceinline__ void gload_lds16(const void* g, void* l) {
    __builtin_amdgcn_global_load_lds(
        (const __attribute__((address_space(1))) unsigned int*)g,
        (__attribute__((address_space(3))) unsigned int*)l, 16, 0, 0);
}

// ---------------------------------------------------------------------------
// Fused fp32->bf16 conversion for all 5 inputs in one launch.
// ---------------------------------------------------------------------------
__global__ __launch_bounds__(256) void cvt_all(
    const float* __restrict__ x,  const float* __restrict__ wq,
    const float* __restrict__ wk, const float* __restrict__ wv,
    const float* __restrict__ wo,
    __hip_bfloat16* __restrict__ xb, __hip_bfloat16* __restrict__ wqkvb,
    __hip_bfloat16* __restrict__ wob) {
    int id = blockIdx.x;
    const float* src; __hip_bfloat16* dst;
    if (id < 4096) { src = x + (size_t)id * 1024; dst = xb + (size_t)id * 1024; }
    else {
        int k = id - 4096, seg = k >> 10;
        size_t off = (size_t)(k & 1023) * 1024;
        if      (seg == 0) { src = wq + off; dst = wqkvb + off; }
        else if (seg == 1) { src = wk + off; dst = wqkvb + (1u << 20) + off; }
        else if (seg == 2) { src = wv + off; dst = wqkvb + (2u << 20) + off; }
        else               { src = wo + off; dst = wob + off; }
    }
    int i = threadIdx.x * 4;
    float4 v = *(const float4*)(src + i);
    dst[i + 0] = __float2bfloat16(v.x);
    dst[i + 1] = __float2bfloat16(v.y);
    dst[i + 2] = __float2bfloat16(v.z);
    dst[i + 3] = __float2bfloat16(v.w);
}

__device__ __forceinline__ void store_c(float* p, float v) { *p = v; }
__device__ __forceinline__ void store_c(__hip_bfloat16* p, float v) {
    *p = __float2bfloat16(v);
}

// ---------------------------------------------------------------------------
// GEMM: C[M,N] = A[M,K] @ B[N,K]^T, 128x128 tile, BK=64 (half the barrier
// drains of BK=32), 4 waves, global_load_lds width-16 staging. LDS tiles are
// chunk-XOR swizzled (c' = c ^ (row&7), 16B chunks): the global SOURCE chunk
// is pre-XOR'd (linear LDS dest — gload_lds writes base+lane*16) and the
// ds_read applies the same XOR -> frag reads spread across banks (was 8-way
// conflict, 3.1M SQ_LDS_BANK_CONFLICT). FUSED=true (QKV projection):
//   blockIdx.y < 16 -> RoPE applied in-register, bf16 store into QKb
//   blockIdx.y >= 16 -> V written TRANSPOSED into Vtg[b][h][d][s'], where
//     s' = s with key-index bits 2<->3 swapped. This pre-permutation makes
//     the attention kernel's in-register P fragments line up with V without
//     ANY cross-lane exchange (the swapped-QK 32x32 C-layout distributes a
//     P-row's keys as (r&3)+8*(r>>2)+4*hi; bit2<->3 swap of the V key index
//     makes the PV contraction use exactly that order on both operands).
// ---------------------------------------------------------------------------
template <typename CT, bool FUSED>
__global__ __launch_bounds__(256) void gemm128(
    const __hip_bfloat16* __restrict__ A,
    const __hip_bfloat16* __restrict__ B,
    CT* __restrict__ C, int K, int ldc,
    __hip_bfloat16* __restrict__ Vtg, const int* __restrict__ pos) {
    __shared__ __hip_bfloat16 As[128 * 64];
    __shared__ __hip_bfloat16 Bs[128 * 64];
    const int t    = threadIdx.x;
    const int wave = t >> 6;
    const int lane = t & 63;
    const int quad = lane >> 4;
    const int l16  = lane & 15;
    const int wy = wave >> 1, wx = wave & 1;
    const int m0 = blockIdx.x * 128, n0 = blockIdx.y * 128;

    // staging: round i covers row (t>>3)+i*32, 16B chunk t&7; source chunk
    // pre-XOR'd so the linear LDS write lands the swizzled layout.
    const int sr  = t >> 3;
    const int scx = (t & 7) ^ (sr & 7);  // (row&7) == (sr&7) for all rounds

    const __hip_bfloat16* Ag = A + (size_t)(m0 + sr) * K + scx * 8;
    const __hip_bfloat16* Bg = B + (size_t)(n0 + sr) * K + scx * 8;

    f32x4 acc[4][4];
#pragma unroll
    for (int i = 0; i < 4; i++)
#pragma unroll
        for (int j = 0; j < 4; j++) acc[i][j] = (f32x4){0.f, 0.f, 0.f, 0.f};

    for (int k0 = 0; k0 < K; k0 += 64) {
        __syncthreads();
#pragma unroll
        for (int i = 0; i < 4; i++) {
            gload_lds16(Ag + (size_t)(i * 32) * K + k0, (char*)As + (t + i * 256) * 16);
            gload_lds16(Bg + (size_t)(i * 32) * K + k0, (char*)Bs + (t + i * 256) * 16);
        }
        __syncthreads();
#pragma unroll
        for (int kk = 0; kk < 2; kk++) {
            bf16x8 af[4], bfr[4];
#pragma unroll
            for (int rb = 0; rb < 4; rb++) {
                int row = wy * 64 + rb * 16 + l16;
                af[rb] = *(const bf16x8*)((const char*)As + row * 128 +
                                          (((kk * 4 + quad) ^ (row & 7)) << 4));
            }
#pragma unroll
            for (int cb = 0; cb < 4; cb++) {
                int row = wx * 64 + cb * 16 + l16;
                bfr[cb] = *(const bf16x8*)((const char*)Bs + row * 128 +
                                           (((kk * 4 + quad) ^ (row & 7)) << 4));
            }
#pragma unroll
            for (int rb = 0; rb < 4; rb++)
#pragma unroll
                for (int cb = 0; cb < 4; cb++)
                    acc[rb][cb] = __builtin_amdgcn_mfma_f32_16x16x32_bf16(
                        af[rb], bfr[cb], acc[rb][cb], 0, 0, 0);
        }
    }

    if (!FUSED || blockIdx.y < 16) {
        if constexpr (FUSED) {
            // ---- fused RoPE on Q/K columns (+0.125 scale on Q) ----
            const float sc = (blockIdx.y < 8) ? 0.125f : 1.0f;
            float fr[4];
#pragma unroll
            for (int cb = 0; cb < 4; cb++) {
                int i = ((cb * 16 + l16) & 63) >> 1;
                fr[cb] = __expf(-(float)(2 * i) * (9.210340371976184f / 64.0f));
            }
            const float par = (l16 & 1) ? 1.f : -1.f;  // odd lane: +pt*sn, even: -pt*sn
#pragma unroll
            for (int rb = 0; rb < 4; rb++)
#pragma unroll
                for (int r = 0; r < 4; r++) {
                    int row = m0 + wy * 64 + rb * 16 + quad * 4 + r;
                    float p = (float)pos[row & (SEQ_LEN - 1)];
#pragma unroll
                    for (int cb = 0; cb < 4; cb++) {
                        float sn, cs;
                        __sincosf(p * fr[cb], &sn, &cs);
                        float v  = acc[rb][cb][r];
                        float pt = __shfl_xor(v, 1);
                        acc[rb][cb][r] = (v * cs + par * pt * sn) * sc;
                    }
                }
        }
#pragma unroll
        for (int rb = 0; rb < 4; rb++)
#pragma unroll
            for (int r = 0; r < 4; r++) {
                size_t ro = (size_t)(m0 + wy * 64 + rb * 16 + quad * 4 + r) * ldc;
#pragma unroll
                for (int cb = 0; cb < 4; cb++)
                    store_c(&C[ro + n0 + wx * 64 + cb * 16 + l16], acc[rb][cb][r]);
            }
    } else {
#pragma unroll
        for (int rb = 0; rb < 4; rb++) {
            int row0 = m0 + wy * 64 + rb * 16 + quad * 4;
            int bb = row0 >> 11, ss = row0 & (SEQ_LEN - 1);
            // key-index bit2<->bit3 swap (see header comment); ss is 4-aligned
            // so the 4 consecutive rows stay consecutive after the swap.
            int ssw = (ss & ~12) | ((ss & 4) << 1) | ((ss & 8) >> 1);
#pragma unroll
            for (int cb = 0; cb < 4; cb++) {
                int vcol = n0 + wx * 64 + cb * 16 + l16 - 2048;
                int hh = vcol >> 6, dd = vcol & 63;
                ushort4 u;
                u.x = (unsigned short)f2b(acc[rb][cb][0]);
                u.y = (unsigned short)f2b(acc[rb][cb][1]);
                u.z = (unsigned short)f2b(acc[rb][cb][2]);
                u.w = (unsigned short)f2b(acc[rb][cb][3]);
                *(ushort4*)(Vtg + ((size_t)(bb * NH + hh) * HD + dd) * SEQ_LEN + ssw) = u;
            }
        }
    }
}

// ---------------------------------------------------------------------------
// Causal MFMA flash attention — 32x32x16 edition (halved LDS traffic).
// Block = 256 thr (4 waves) = one 128-row q-tile; wave w owns rows w*32..+31
// via 32x32x16 MFMA (32 q-rows/wave halves per-row LDS cost: every wave must
// read the full K/V tile regardless of rows owned; trips also halve).
// SWAPPED QK^T (mfma(K,Q)) -> lane (l5,hi) owns P[q=row0+l5][keys crow(r,hi)]
// with crow = (r&3)+8*(r>>2)+4*hi. P->PV A-frags are packed IN ORDER (no
// cross-lane exchange, no inline asm): the V tile was pre-stored with key
// bits 2<->3 swapped, which makes the PV contraction's k-slot order equal to
// the natural register order on both operands. Zero P-LDS roundtrip.
// K/V async-staged to LDS (zero VGPR), chunk-XOR swizzled (pre-swizzled
// global source + swizzled ds_read). Grid 512: id%8 = (b,h)%8 pins all
// blocks of one (b,h) to one XCD (proven FETCH 55->12 MB); qt decode pairs
// blocks id and id+256 to a constant 34 trips for load balance.
// ---------------------------------------------------------------------------
__global__ __launch_bounds__(256, 2) void attn_kernel(
    const __hip_bfloat16* __restrict__ QK,
    const __hip_bfloat16* __restrict__ Vtg,
    __hip_bfloat16* __restrict__ O) {
    __shared__ __hip_bfloat16 Ks[2][64 * 64];  // [buf][key][d]  XOR-swizzled
    __shared__ __hip_bfloat16 Vs[2][64 * 64];  // [buf][d][key'] XOR-swizzled

    const int t    = threadIdx.x;
    const int wave = t >> 6;        // 0..3
    const int lane = t & 63;
    const int l5   = lane & 31;     // row within a 32-block
    const int hi   = lane >> 5;     // k-half of the fragment
    const int id   = blockIdx.x;
    const int qtc  = id >> 5;       // 0..15
    const int hb   = id & 31;
    const int h    = hb & 15;
    const int b    = hb >> 4;
    // pairing: blocks id and id+256 get qt = 15-c and c -> trips sum = 34
    const int qt   = (qtc < 8) ? (15 - qtc) : (qtc - 8);

    const int row0 = qt * 128 + wave * 32;  // this wave's first q row
    const int ktd  = (row0 + 31) >> 6;      // wave's last useful k-tile
    const int KTM  = 2 * qt + 1;            // block's last k-tile

    const int sr  = t >> 3;                 // staging row 0..31 (and +32)
    const int scx = (t & 7) ^ (sr & 7);     // pre-swizzled source chunk

    const __hip_bfloat16* kbase = QK + (size_t)(b * SEQ_LEN) * LDQK + DM + h * HD;
    const __hip_bfloat16* vbase = Vtg + (size_t)((b * NH + h) * HD) * SEQ_LEN;

    // Q fragments (B-operand of swapped QK^T): lane holds Q[row0+l5][dc*16+hi*8+j]
    bf16x8 qf[4];
    {
        const __hip_bfloat16* qp =
            QK + (size_t)(b * SEQ_LEN + row0 + l5) * LDQK + h * HD + hi * 8;
#pragma unroll
        for (int dc = 0; dc < 4; dc++) qf[dc] = *(const bf16x8*)(qp + dc * 16);
    }

    f32x16 o0, o1;
#pragma unroll
    for (int i = 0; i < 16; i++) { o0[i] = 0.f; o1[i] = 0.f; }
    float l_acc = 0.f;

#define STAGE(BUF, KT)                                                          \
    {                                                                           \
        gload_lds16(kbase + (size_t)((KT) * 64 + sr) * LDQK + scx * 8,          \
                    (char*)&Ks[BUF][0] + t * 16);                               \
        gload_lds16(kbase + (size_t)((KT) * 64 + sr + 32) * LDQK + scx * 8,     \
                    (char*)&Ks[BUF][0] + (t + 256) * 16);                       \
        gload_lds16(vbase + (size_t)sr * SEQ_LEN + (KT) * 64 + scx * 8,         \
                    (char*)&Vs[BUF][0] + t * 16);                               \
        gload_lds16(vbase + (size_t)(sr + 32) * SEQ_LEN + (KT) * 64 + scx * 8,  \
                    (char*)&Vs[BUF][0] + (t + 256) * 16);                       \
    }

// swizzled 16B fragment read: row ROW, 16B chunk CH (8 bf16)
#define LFRAG(BASE, ROW, CH)                                                    \
    (*(const bf16x8*)((const char*)(BASE) + (ROW) * 128 + ((((CH) ^ ((ROW) & 7))) << 4)))

// exp + pack one kblock's S (f32x16) into two PV A-frags, NATURAL ORDER:
// PA0[j] = p[j] (keys crow(j,hi)), PA1[j] = p[8+j]. V's bit2<->3 key permute
// makes this exactly the k-slot order of the V fragments below.
#define MKPA(S, PA0, PA1)                                                       \
    {                                                                           \
        float p_[16];                                                           \
        _Pragma("unroll") for (int r = 0; r < 16; r++) {                        \
            p_[r] = __expf((S)[r]);                                             \
            l_acc += p_[r];                                                     \
        }                                                                       \
        _Pragma("unroll") for (int j = 0; j < 8; j++) {                         \
            PA0[j] = f2b(p_[j]);                                                \
            PA1[j] = f2b(p_[8 + j]);                                            \
        }                                                                       \
    }

// one K-tile trip: S^T = K Q^T (swapped), mask, p=exp(s), O += P V
#define TRIP(BUF, KT)                                                           \
    {                                                                           \
        f32x16 s0, s1;                                                          \
        _Pragma("unroll") for (int i = 0; i < 16; i++) { s0[i] = 0.f; s1[i] = 0.f; } \
        __builtin_amdgcn_s_setprio(1);                                          \
        _Pragma("unroll") for (int dc = 0; dc < 4; dc++) {                      \
            bf16x8 k0f = LFRAG(Ks[BUF], l5, dc * 2 + hi);                       \
            bf16x8 k1f = LFRAG(Ks[BUF], 32 + l5, dc * 2 + hi);                  \
            s0 = __builtin_amdgcn_mfma_f32_32x32x16_bf16(k0f, qf[dc], s0, 0, 0, 0); \
            s1 = __builtin_amdgcn_mfma_f32_32x32x16_bf16(k1f, qf[dc], s1, 0, 0, 0); \
        }                                                                       \
        __builtin_amdgcn_s_setprio(0);                                          \
        if ((KT) == ktd) { /* causal mask on the diagonal tile */               \
            int qrow = row0 + l5;                                               \
            _Pragma("unroll") for (int r = 0; r < 16; r++) {                    \
                int key = (KT) * 64 + (r & 3) + 8 * (r >> 2) + 4 * hi;          \
                if (key > qrow) s0[r] = -1e30f;                                 \
                if (key + 32 > qrow) s1[r] = -1e30f;                            \
            }                                                                   \
        }                                                                       \
        bf16x8 pa0, pa1, pa2, pa3;                                              \
        MKPA(s0, pa0, pa1);                                                     \
        MKPA(s1, pa2, pa3);                                                     \
        __builtin_amdgcn_s_setprio(1);                                          \
        _Pragma("unroll") for (int kc = 0; kc < 4; kc++) {                      \
            bf16x8 v0f = LFRAG(Vs[BUF], l5, kc * 2 + hi);                       \
            bf16x8 v1f = LFRAG(Vs[BUF], 32 + l5, kc * 2 + hi);                  \
            bf16x8 paf = (kc == 0) ? pa0 : (kc == 1) ? pa1 : (kc == 2) ? pa2 : pa3; \
            o0 = __builtin_amdgcn_mfma_f32_32x32x16_bf16(paf, v0f, o0, 0, 0, 0); \
            o1 = __builtin_amdgcn_mfma_f32_32x32x16_bf16(paf, v1f, o1, 0, 0, 0); \
        }                                                                       \
        __builtin_amdgcn_s_setprio(0);                                          \
    }

    STAGE(0, 0);
    for (int kt = 0; kt <= KTM; ++kt) {
        const int buf = kt & 1;
        __syncthreads();  // staging of buf drained; buf^1 free for reuse
        if (kt < KTM) STAGE(buf ^ 1, kt + 1);  // async; hides under TRIP
        if (kt <= ktd) TRIP(buf, kt);          // waves 0/1 skip fully-masked tail
    }

    // ---- epilogue ----
    // lane's l_acc is the partial row-sum for qrow = row0 + l5; partner lane
    // lane^32 holds the complementary key halves of the same row.
    l_acc += __shfl_xor(l_acc, 32);
    float inv = 1.0f / l_acc;
    // O element (reg r) sits at qrow = row0 + crow(r,hi): fetch that row's inv
#pragma unroll
    for (int r = 0; r < 16; r++) {
        int crow  = (r & 3) + 8 * (r >> 2) + 4 * hi;
        float invr = __shfl(inv, crow);  // lanes 0..31 hold inv for row0+lane
        size_t ro = (size_t)(b * SEQ_LEN + row0 + crow) * DM + h * HD;
        O[ro + l5]      = __float2bfloat16(o0[r] * invr);
        O[ro + 32 + l5] = __float2bfloat16(o1[r] * invr);
    }
#undef STAGE
#undef LFRAG
#undef MKPA
#undef TRIP
}

// ---------------------------------------------------------------------------
// Workspace (40 MiB of 48):
//   [0,8)    xb [4096x1024] bf16, reused as Ab (attn output)
//   [8,14)   Wqkvb [3072x1024] bf16
//   [14,16)  Wob [1024x1024] bf16
//   [16,32)  QKb [4096x2048] bf16 (Q roped+scaled, K roped — fused in GEMM)
//   [32,40)  Vtg [2][16][64][2048] bf16 (key bits 2<->3 swapped layout)
// ---------------------------------------------------------------------------
extern "C" void kernel_launch(void* const* d_in, const int* in_sizes, int n_in,
                              void* d_out, int out_size, void* d_ws, size_t ws_size,
                              hipStream_t stream) {
    const float* x  = (const float*)d_in[0];
    const float* Wq = (const float*)d_in[1];
    const float* Wk = (const float*)d_in[2];
    const float* Wv = (const float*)d_in[3];
    const float* Wo = (const float*)d_in[4];
    const int* pos = (const int*)d_in[6];
    float* out = (float*)d_out;

    char* w = (char*)d_ws;
    const size_t MiB = 1024 * 1024;
    __hip_bfloat16* xb    = (__hip_bfloat16*)(w + 0 * MiB);
    __hip_bfloat16* Ab    = (__hip_bfloat16*)(w + 0 * MiB);  // reuse after QKV gemm
    __hip_bfloat16* Wqkvb = (__hip_bfloat16*)(w + 8 * MiB);
    __hip_bfloat16* Wob   = (__hip_bfloat16*)(w + 14 * MiB);
    __hip_bfloat16* QKb   = (__hip_bfloat16*)(w + 16 * MiB);
    __hip_bfloat16* Vtg   = (__hip_bfloat16*)(w + 32 * MiB);

    cvt_all<<<8192, 256, 0, stream>>>(x, Wq, Wk, Wv, Wo, xb, Wqkvb, Wob);

    gemm128<__hip_bfloat16, true><<<dim3(NR / 128, NQKV / 128), 256, 0, stream>>>(
        xb, Wqkvb, QKb, DM, LDQK, Vtg, pos);

    attn_kernel<<<512, 256, 0, stream>>>(QKb, Vtg, Ab);

    gemm128<float, false><<<dim3(NR / 128, DM / 128), 256, 0, stream>>>(
        Ab, Wob, out, DM, DM, nullptr, nullptr);
}

// Round 6
// 196.548 us; speedup vs baseline: 1.0222x; 1.0222x over previous
//
#include <hip/hip_runtime.h>
#include <hip/hip_bf16.h>

#define SEQ_LEN 2048
#define NBATCH 2
#define DM 1024
#define NH 16
#define HD 64
#define NR (NBATCH * SEQ_LEN)  // 4096 rows
#define NQKV (3 * DM)          // 3072 fused QKV cols
#define LDQK 2048              // QK buffer leading dim (Q cols 0..1023, K 1024..2047)

typedef __attribute__((ext_vector_type(8))) short bf16x8;
typedef __attribute__((ext_vector_type(4))) float f32x4;
typedef __attribute__((ext_vector_type(16))) float f32x16;

__device__ __forceinline__ short f2b(float f) {
    __hip_bfloat16 h = __float2bfloat16(f);
    return *reinterpret_cast<short*>(&h);
}

// async global->LDS 16B copy
__device__ __forceinline__ void gload_lds16(const void* g, void* l) {
    __builtin_amdgcn_global_load_lds(
        (const __attribute__((address_space(1))) unsigned int*)g,
        (__attribute__((address_space(3))) unsigned int*)l, 16, 0, 0);
}

// ---------------------------------------------------------------------------
// Fused fp32->bf16 conversion for all 5 inputs in one launch.
// ---------------------------------------------------------------------------
__global__ __launch_bounds__(256) void cvt_all(
    const float* __restrict__ x,  const float* __restrict__ wq,
    const float* __restrict__ wk, const float* __restrict__ wv,
    const float* __restrict__ wo,
    __hip_bfloat16* __restrict__ xb, __hip_bfloat16* __restrict__ wqkvb,
    __hip_bfloat16* __restrict__ wob) {
    int id = blockIdx.x;
    const float* src; __hip_bfloat16* dst;
    if (id < 4096) { src = x + (size_t)id * 1024; dst = xb + (size_t)id * 1024; }
    else {
        int k = id - 4096, seg = k >> 10;
        size_t off = (size_t)(k & 1023) * 1024;
        if      (seg == 0) { src = wq + off; dst = wqkvb + off; }
        else if (seg == 1) { src = wk + off; dst = wqkvb + (1u << 20) + off; }
        else if (seg == 2) { src = wv + off; dst = wqkvb + (2u << 20) + off; }
        else               { src = wo + off; dst = wob + off; }
    }
    int i = threadIdx.x * 4;
    float4 v = *(const float4*)(src + i);
    dst[i + 0] = __float2bfloat16(v.x);
    dst[i + 1] = __float2bfloat16(v.y);
    dst[i + 2] = __float2bfloat16(v.z);
    dst[i + 3] = __float2bfloat16(v.w);
}

__device__ __forceinline__ void store_c(float* p, float v) { *p = v; }
__device__ __forceinline__ void store_c(__hip_bfloat16* p, float v) {
    *p = __float2bfloat16(v);
}

// ---------------------------------------------------------------------------
// GEMM: C[M,N] = A[M,K] @ B[N,K]^T, 128x128 tile, BK=32, 4 waves,
// DOUBLE-BUFFERED LDS (T3-minimum 2-phase): stage tile t+1 into buf^1 while
// computing tile t from buf -> the global-load latency (the 2-phase
// structure's dominant cost, m233) hides under ds_read+MFMA. ONE barrier per
// iteration (compiler emits the vmcnt(0)+lgkmcnt(0) drain before s_barrier).
// LDS tiles chunk-XOR swizzled over 4 chunks (c' = c ^ (row&3)) via
// pre-swizzled global source + swizzled ds_read (both-sides rule); residual
// 4-way conflict, off the critical path at 2ph. Grid is FLAT with
// XCD-chunked decode (T1): wg = (id%8)*(nwg/8) + id/8, bx = wg % nbx ->
// each XCD gets a contiguous chunk that reuses B-panels in its L2.
// FUSED=true (QKV projection):
//   by < 16 -> RoPE applied in-register, bf16 store into QKb
//   by >= 16 -> V written TRANSPOSED into Vtg[b][h][d][s'], where s' = s
//     with key-index bits 2<->3 swapped (matches attn's in-register P order).
// ---------------------------------------------------------------------------
template <typename CT, bool FUSED>
__global__ __launch_bounds__(256) void gemm128(
    const __hip_bfloat16* __restrict__ A,
    const __hip_bfloat16* __restrict__ B,
    CT* __restrict__ C, int K, int ldc,
    __hip_bfloat16* __restrict__ Vtg, const int* __restrict__ pos, int nbx) {
    __shared__ __hip_bfloat16 As[2][128 * 32];
    __shared__ __hip_bfloat16 Bs[2][128 * 32];
    const int t    = threadIdx.x;
    const int wave = t >> 6;
    const int lane = t & 63;
    const int quad = lane >> 4;
    const int l16  = lane & 15;
    const int wy = wave >> 1, wx = wave & 1;

    // XCD-chunked bijective decode (nwg % 8 == 0 for both launches)
    const int nwg = gridDim.x;
    const int wg  = (blockIdx.x & 7) * (nwg >> 3) + (blockIdx.x >> 3);
    const int bx  = wg % nbx;
    const int by  = wg / nbx;
    const int m0 = bx * 128, n0 = by * 128;

    // staging: round i covers row (t>>2)+i*64, 16B chunk t&3; source chunk
    // pre-XOR'd so the linear LDS write lands the swizzled layout.
    const int sr  = t >> 2;              // 0..63 (and +64)
    const int scx = (t & 3) ^ (sr & 3);  // (row&3) == (sr&3) for both rounds

    const __hip_bfloat16* Ag = A + (size_t)(m0 + sr) * K + scx * 8;
    const __hip_bfloat16* Bg = B + (size_t)(n0 + sr) * K + scx * 8;

#define GSTAGE(BUF, K0)                                                         \
    {                                                                           \
        gload_lds16(Ag + (K0), (char*)As[BUF] + t * 16);                        \
        gload_lds16(Ag + (size_t)64 * K + (K0), (char*)As[BUF] + (t + 256) * 16); \
        gload_lds16(Bg + (K0), (char*)Bs[BUF] + t * 16);                        \
        gload_lds16(Bg + (size_t)64 * K + (K0), (char*)Bs[BUF] + (t + 256) * 16); \
    }

    f32x4 acc[4][4];
#pragma unroll
    for (int i = 0; i < 4; i++)
#pragma unroll
        for (int j = 0; j < 4; j++) acc[i][j] = (f32x4){0.f, 0.f, 0.f, 0.f};

    const int NT = K >> 5;  // BK=32 iterations
    GSTAGE(0, 0);
    __syncthreads();  // buf0 staged (compiler drains vmcnt before barrier)
    int cur = 0;
    for (int t32 = 0; t32 < NT; ++t32) {
        if (t32 + 1 < NT) GSTAGE(cur ^ 1, (t32 + 1) * 32);  // async prefetch

        bf16x8 af[4], bfr[4];
#pragma unroll
        for (int rb = 0; rb < 4; rb++) {
            int row = wy * 64 + rb * 16 + l16;
            af[rb] = *(const bf16x8*)((const char*)As[cur] + row * 64 +
                                      ((quad ^ (row & 3)) << 4));
        }
#pragma unroll
        for (int cb = 0; cb < 4; cb++) {
            int row = wx * 64 + cb * 16 + l16;
            bfr[cb] = *(const bf16x8*)((const char*)Bs[cur] + row * 64 +
                                       ((quad ^ (row & 3)) << 4));
        }
#pragma unroll
        for (int rb = 0; rb < 4; rb++)
#pragma unroll
            for (int cb = 0; cb < 4; cb++)
                acc[rb][cb] = __builtin_amdgcn_mfma_f32_16x16x32_bf16(
                    af[rb], bfr[cb], acc[rb][cb], 0, 0, 0);

        __syncthreads();  // drains prefetch vmcnt + guards buf reuse
        cur ^= 1;
    }
#undef GSTAGE

    if (!FUSED || by < 16) {
        if constexpr (FUSED) {
            // ---- fused RoPE on Q/K columns (+0.125 scale on Q) ----
            const float sc = (by < 8) ? 0.125f : 1.0f;
            float fr[4];
#pragma unroll
            for (int cb = 0; cb < 4; cb++) {
                int i = ((cb * 16 + l16) & 63) >> 1;
                fr[cb] = __expf(-(float)(2 * i) * (9.210340371976184f / 64.0f));
            }
            const float par = (l16 & 1) ? 1.f : -1.f;  // odd lane: +pt*sn, even: -pt*sn
#pragma unroll
            for (int rb = 0; rb < 4; rb++)
#pragma unroll
                for (int r = 0; r < 4; r++) {
                    int row = m0 + wy * 64 + rb * 16 + quad * 4 + r;
                    float p = (float)pos[row & (SEQ_LEN - 1)];
#pragma unroll
                    for (int cb = 0; cb < 4; cb++) {
                        float sn, cs;
                        __sincosf(p * fr[cb], &sn, &cs);
                        float v  = acc[rb][cb][r];
                        float pt = __shfl_xor(v, 1);
                        acc[rb][cb][r] = (v * cs + par * pt * sn) * sc;
                    }
                }
        }
#pragma unroll
        for (int rb = 0; rb < 4; rb++)
#pragma unroll
            for (int r = 0; r < 4; r++) {
                size_t ro = (size_t)(m0 + wy * 64 + rb * 16 + quad * 4 + r) * ldc;
#pragma unroll
                for (int cb = 0; cb < 4; cb++)
                    store_c(&C[ro + n0 + wx * 64 + cb * 16 + l16], acc[rb][cb][r]);
            }
    } else {
#pragma unroll
        for (int rb = 0; rb < 4; rb++) {
            int row0 = m0 + wy * 64 + rb * 16 + quad * 4;
            int bb = row0 >> 11, ss = row0 & (SEQ_LEN - 1);
            // key-index bit2<->bit3 swap (see header comment); ss is 4-aligned
            // so the 4 consecutive rows stay consecutive after the swap.
            int ssw = (ss & ~12) | ((ss & 4) << 1) | ((ss & 8) >> 1);
#pragma unroll
            for (int cb = 0; cb < 4; cb++) {
                int vcol = n0 + wx * 64 + cb * 16 + l16 - 2048;
                int hh = vcol >> 6, dd = vcol & 63;
                ushort4 u;
                u.x = (unsigned short)f2b(acc[rb][cb][0]);
                u.y = (unsigned short)f2b(acc[rb][cb][1]);
                u.z = (unsigned short)f2b(acc[rb][cb][2]);
                u.w = (unsigned short)f2b(acc[rb][cb][3]);
                *(ushort4*)(Vtg + ((size_t)(bb * NH + hh) * HD + dd) * SEQ_LEN + ssw) = u;
            }
        }
    }
}

// ---------------------------------------------------------------------------
// Causal MFMA flash attention — 32x32x16 edition (halved LDS traffic).
// Block = 256 thr (4 waves) = one 128-row q-tile; wave w owns rows w*32..+31
// via 32x32x16 MFMA (32 q-rows/wave halves per-row LDS cost: every wave must
// read the full K/V tile regardless of rows owned; trips also halve).
// SWAPPED QK^T (mfma(K,Q)) -> lane (l5,hi) owns P[q=row0+l5][keys crow(r,hi)]
// with crow = (r&3)+8*(r>>2)+4*hi. P->PV A-frags are packed IN ORDER (no
// cross-lane exchange, no inline asm): the V tile was pre-stored with key
// bits 2<->3 swapped, which makes the PV contraction's k-slot order equal to
// the natural register order on both operands. Zero P-LDS roundtrip.
// K/V async-staged to LDS (zero VGPR), chunk-XOR swizzled (pre-swizzled
// global source + swizzled ds_read). Grid 512: id%8 = (b,h)%8 pins all
// blocks of one (b,h) to one XCD (proven FETCH 55->12 MB); qt decode pairs
// blocks id and id+256 to a constant 34 trips for load balance.
// ---------------------------------------------------------------------------
__global__ __launch_bounds__(256, 2) void attn_kernel(
    const __hip_bfloat16* __restrict__ QK,
    const __hip_bfloat16* __restrict__ Vtg,
    __hip_bfloat16* __restrict__ O) {
    __shared__ __hip_bfloat16 Ks[2][64 * 64];  // [buf][key][d]  XOR-swizzled
    __shared__ __hip_bfloat16 Vs[2][64 * 64];  // [buf][d][key'] XOR-swizzled

    const int t    = threadIdx.x;
    const int wave = t >> 6;        // 0..3
    const int lane = t & 63;
    const int l5   = lane & 31;     // row within a 32-block
    const int hi   = lane >> 5;     // k-half of the fragment
    const int id   = blockIdx.x;
    const int qtc  = id >> 5;       // 0..15
    const int hb   = id & 31;
    const int h    = hb & 15;
    const int b    = hb >> 4;
    // pairing: blocks id and id+256 get qt = 15-c and c -> trips sum = 34
    const int qt   = (qtc < 8) ? (15 - qtc) : (qtc - 8);

    const int row0 = qt * 128 + wave * 32;  // this wave's first q row
    const int ktd  = (row0 + 31) >> 6;      // wave's last useful k-tile
    const int KTM  = 2 * qt + 1;            // block's last k-tile

    const int sr  = t >> 3;                 // staging row 0..31 (and +32)
    const int scx = (t & 7) ^ (sr & 7);     // pre-swizzled source chunk

    const __hip_bfloat16* kbase = QK + (size_t)(b * SEQ_LEN) * LDQK + DM + h * HD;
    const __hip_bfloat16* vbase = Vtg + (size_t)((b * NH + h) * HD) * SEQ_LEN;

    // Q fragments (B-operand of swapped QK^T): lane holds Q[row0+l5][dc*16+hi*8+j]
    bf16x8 qf[4];
    {
        const __hip_bfloat16* qp =
            QK + (size_t)(b * SEQ_LEN + row0 + l5) * LDQK + h * HD + hi * 8;
#pragma unroll
        for (int dc = 0; dc < 4; dc++) qf[dc] = *(const bf16x8*)(qp + dc * 16);
    }

    f32x16 o0, o1;
#pragma unroll
    for (int i = 0; i < 16; i++) { o0[i] = 0.f; o1[i] = 0.f; }
    float l_acc = 0.f;

#define STAGE(BUF, KT)                                                          \
    {                                                                           \
        gload_lds16(kbase + (size_t)((KT) * 64 + sr) * LDQK + scx * 8,          \
                    (char*)&Ks[BUF][0] + t * 16);                               \
        gload_lds16(kbase + (size_t)((KT) * 64 + sr + 32) * LDQK + scx * 8,     \
                    (char*)&Ks[BUF][0] + (t + 256) * 16);                       \
        gload_lds16(vbase + (size_t)sr * SEQ_LEN + (KT) * 64 + scx * 8,         \
                    (char*)&Vs[BUF][0] + t * 16);                               \
        gload_lds16(vbase + (size_t)(sr + 32) * SEQ_LEN + (KT) * 64 + scx * 8,  \
                    (char*)&Vs[BUF][0] + (t + 256) * 16);                       \
    }

// swizzled 16B fragment read: row ROW, 16B chunk CH (8 bf16)
#define LFRAG(BASE, ROW, CH)                                                    \
    (*(const bf16x8*)((const char*)(BASE) + (ROW) * 128 + ((((CH) ^ ((ROW) & 7))) << 4)))

// exp + pack one kblock's S (f32x16) into two PV A-frags, NATURAL ORDER:
// PA0[j] = p[j] (keys crow(j,hi)), PA1[j] = p[8+j]. V's bit2<->3 key permute
// makes this exactly the k-slot order of the V fragments below.
#define MKPA(S, PA0, PA1)                                                       \
    {                                                                           \
        float p_[16];                                                           \
        _Pragma("unroll") for (int r = 0; r < 16; r++) {                        \
            p_[r] = __expf((S)[r]);                                             \
            l_acc += p_[r];                                                     \
        }                                                                       \
        _Pragma("unroll") for (int j = 0; j < 8; j++) {                         \
            PA0[j] = f2b(p_[j]);                                                \
            PA1[j] = f2b(p_[8 + j]);                                            \
        }                                                                       \
    }

// one K-tile trip: S^T = K Q^T (swapped), mask, p=exp(s), O += P V
#define TRIP(BUF, KT)                                                           \
    {                                                                           \
        f32x16 s0, s1;                                                          \
        _Pragma("unroll") for (int i = 0; i < 16; i++) { s0[i] = 0.f; s1[i] = 0.f; } \
        __builtin_amdgcn_s_setprio(1);                                          \
        _Pragma("unroll") for (int dc = 0; dc < 4; dc++) {                      \
            bf16x8 k0f = LFRAG(Ks[BUF], l5, dc * 2 + hi);                       \
            bf16x8 k1f = LFRAG(Ks[BUF], 32 + l5, dc * 2 + hi);                  \
            s0 = __builtin_amdgcn_mfma_f32_32x32x16_bf16(k0f, qf[dc], s0, 0, 0, 0); \
            s1 = __builtin_amdgcn_mfma_f32_32x32x16_bf16(k1f, qf[dc], s1, 0, 0, 0); \
        }                                                                       \
        __builtin_amdgcn_s_setprio(0);                                          \
        if ((KT) == ktd) { /* causal mask on the diagonal tile */               \
            int qrow = row0 + l5;                                               \
            _Pragma("unroll") for (int r = 0; r < 16; r++) {                    \
                int key = (KT) * 64 + (r & 3) + 8 * (r >> 2) + 4 * hi;          \
                if (key > qrow) s0[r] = -1e30f;                                 \
                if (key + 32 > qrow) s1[r] = -1e30f;                            \
            }                                                                   \
        }                                                                       \
        bf16x8 pa0, pa1, pa2, pa3;                                              \
        MKPA(s0, pa0, pa1);                                                     \
        MKPA(s1, pa2, pa3);                                                     \
        __builtin_amdgcn_s_setprio(1);                                          \
        _Pragma("unroll") for (int kc = 0; kc < 4; kc++) {                      \
            bf16x8 v0f = LFRAG(Vs[BUF], l5, kc * 2 + hi);                       \
            bf16x8 v1f = LFRAG(Vs[BUF], 32 + l5, kc * 2 + hi);                  \
            bf16x8 paf = (kc == 0) ? pa0 : (kc == 1) ? pa1 : (kc == 2) ? pa2 : pa3; \
            o0 = __builtin_amdgcn_mfma_f32_32x32x16_bf16(paf, v0f, o0, 0, 0, 0); \
            o1 = __builtin_amdgcn_mfma_f32_32x32x16_bf16(paf, v1f, o1, 0, 0, 0); \
        }                                                                       \
        __builtin_amdgcn_s_setprio(0);                                          \
    }

    STAGE(0, 0);
    for (int kt = 0; kt <= KTM; ++kt) {
        const int buf = kt & 1;
        __syncthreads();  // staging of buf drained; buf^1 free for reuse
        if (kt < KTM) STAGE(buf ^ 1, kt + 1);  // async; hides under TRIP
        if (kt <= ktd) TRIP(buf, kt);          // waves 0/1 skip fully-masked tail
    }

    // ---- epilogue ----
    // lane's l_acc is the partial row-sum for qrow = row0 + l5; partner lane
    // lane^32 holds the complementary key halves of the same row.
    l_acc += __shfl_xor(l_acc, 32);
    float inv = 1.0f / l_acc;
    // O element (reg r) sits at qrow = row0 + crow(r,hi): fetch that row's inv
#pragma unroll
    for (int r = 0; r < 16; r++) {
        int crow  = (r & 3) + 8 * (r >> 2) + 4 * hi;
        float invr = __shfl(inv, crow);  // lanes 0..31 hold inv for row0+lane
        size_t ro = (size_t)(b * SEQ_LEN + row0 + crow) * DM + h * HD;
        O[ro + l5]      = __float2bfloat16(o0[r] * invr);
        O[ro + 32 + l5] = __float2bfloat16(o1[r] * invr);
    }
#undef STAGE
#undef LFRAG
#undef MKPA
#undef TRIP
}

// ---------------------------------------------------------------------------
// Workspace (40 MiB of 48):
//   [0,8)    xb [4096x1024] bf16, reused as Ab (attn output)
//   [8,14)   Wqkvb [3072x1024] bf16
//   [14,16)  Wob [1024x1024] bf16
//   [16,32)  QKb [4096x2048] bf16 (Q roped+scaled, K roped — fused in GEMM)
//   [32,40)  Vtg [2][16][64][2048] bf16 (key bits 2<->3 swapped layout)
// ---------------------------------------------------------------------------
extern "C" void kernel_launch(void* const* d_in, const int* in_sizes, int n_in,
                              void* d_out, int out_size, void* d_ws, size_t ws_size,
                              hipStream_t stream) {
    const float* x  = (const float*)d_in[0];
    const float* Wq = (const float*)d_in[1];
    const float* Wk = (const float*)d_in[2];
    const float* Wv = (const float*)d_in[3];
    const float* Wo = (const float*)d_in[4];
    const int* pos = (const int*)d_in[6];
    float* out = (float*)d_out;

    char* w = (char*)d_ws;
    const size_t MiB = 1024 * 1024;
    __hip_bfloat16* xb    = (__hip_bfloat16*)(w + 0 * MiB);
    __hip_bfloat16* Ab    = (__hip_bfloat16*)(w + 0 * MiB);  // reuse after QKV gemm
    __hip_bfloat16* Wqkvb = (__hip_bfloat16*)(w + 8 * MiB);
    __hip_bfloat16* Wob   = (__hip_bfloat16*)(w + 14 * MiB);
    __hip_bfloat16* QKb   = (__hip_bfloat16*)(w + 16 * MiB);
    __hip_bfloat16* Vtg   = (__hip_bfloat16*)(w + 32 * MiB);

    cvt_all<<<8192, 256, 0, stream>>>(x, Wq, Wk, Wv, Wo, xb, Wqkvb, Wob);

    // flat grids (nwg % 8 == 0), XCD-chunked decode inside; nbx = M/128 = 32
    gemm128<__hip_bfloat16, true><<<(NR / 128) * (NQKV / 128), 256, 0, stream>>>(
        xb, Wqkvb, QKb, DM, LDQK, Vtg, pos, NR / 128);

    attn_kernel<<<512, 256, 0, stream>>>(QKb, Vtg, Ab);

    gemm128<float, false><<<(NR / 128) * (DM / 128), 256, 0, stream>>>(
        Ab, Wob, out, DM, DM, nullptr, nullptr, NR / 128);
}